// Round 4
// baseline (195.855 us; speedup 1.0000x reference)
//
#include <hip/hip_runtime.h>
#include <math.h>

#define N_    32
#define CIN   128
#define H_    56
#define W_    56
#define COUT  256
#define OH    28
#define OW    28
#define M_    (N_ * OH * OW)      // 25088
#define EPS_  0.007f

typedef unsigned short U16;
typedef float f32x4  __attribute__((ext_vector_type(4)));
typedef short bf16x8 __attribute__((ext_vector_type(8)));

// ws float-region layout
#define SCALE_IDX 0
#define ZERO_IDX  8             // wsf[8..15]: 32B zero page for OOB global_load_lds
#define WSQ_IDX   16            // 256 floats
#define PSQ_IDX   512           // 25088 floats
#define U16_BYTE_OFF 102400     // = 25600 floats, 256B aligned

__device__ __forceinline__ U16 f2bf(float f) {
    unsigned int u = __builtin_bit_cast(unsigned int, f);
    u = (u + 0x7fffu + ((u >> 16) & 1u)) >> 16;   // RNE
    return (U16)u;
}
__device__ __forceinline__ float b2f(U16 h) {
    unsigned int u = ((unsigned int)h) << 16;
    return __builtin_bit_cast(float, u);
}

__device__ __forceinline__ void gl_lds16(const U16* g, U16* l) {
    __builtin_amdgcn_global_load_lds((const __attribute__((address_space(1))) void*)g,
                                     (__attribute__((address_space(3))) void*)l, 16, 0, 0);
}

// ---------------- fused prep: x transpose + weight reorder + wsq/scale/zero ----------------
// blocks [0,6272)            : NCHW f32 -> NHWC bf16
// blocks [6272,9856)         : weight reorder to B'[co][k] bf16
// blocks [9856,10112)        : per-filter sqnorm + alpha scale + zero page
__global__ void k_prep(const float* __restrict__ x,
                       const float* __restrict__ w_yat,
                       const float* __restrict__ w_lin,
                       const float* __restrict__ w_short,
                       const float* __restrict__ alpha,
                       U16* __restrict__ xt, U16* __restrict__ B1,
                       U16* __restrict__ B3, U16* __restrict__ B2,
                       float* __restrict__ wsf) {
    int b = blockIdx.x, t = threadIdx.x;
    if (b < 6272) {
        int idx = b * 256 + t;                     // 1,605,632 exactly
        int ci8 = idx & 15;
        int px  = idx >> 4;                        // n*3136 + hw
        int n   = px / 3136;
        int hw  = px - n * 3136;
        const float* src = x + ((size_t)n * 128 + ci8 * 8) * 3136 + hw;
        unsigned int o[4];
#pragma unroll
        for (int j = 0; j < 4; ++j) {
            float a = src[(size_t)(2 * j)     * 3136];
            float c = src[(size_t)(2 * j + 1) * 3136];
            o[j] = (unsigned)f2bf(a) | ((unsigned)f2bf(c) << 16);
        }
        *(uint4*)&xt[(size_t)px * 128 + ci8 * 8] = *(const uint4*)o;
    } else if (b < 9856) {
        int idx = (b - 6272) * 256 + t;            // 917,504 exactly
        if (idx < 294912) {
            int co = idx / 1152, k = idx % 1152;
            int khkw = k >> 7, ci = k & 127;
            B1[idx] = f2bf(w_yat[(co * 128 + ci) * 9 + khkw]);
        } else if (idx < 294912 + 589824) {
            int i2 = idx - 294912;
            int co = i2 / 2304, k = i2 % 2304;
            int khkw = k >> 8, cy = k & 255;
            B3[i2] = f2bf(w_lin[(co * 256 + cy) * 9 + khkw]);
        } else {
            int i3 = idx - (294912 + 589824);      // < 32768
            B2[i3] = f2bf(w_short[i3]);
        }
    } else {
        int co = b - 9856, lane = t & 63, wv = t >> 6;
        const float* wc = w_yat + (size_t)co * 1152;
        float s = 0.f;
        for (int i = t; i < 1152; i += 256) { float v = wc[i]; s += v * v; }
#pragma unroll
        for (int off = 32; off >= 1; off >>= 1) s += __shfl_xor(s, off);
        __shared__ float red[4];
        if (lane == 0) red[wv] = s;
        __syncthreads();
        if (t == 0) {
            wsf[WSQ_IDX + co] = red[0] + red[1] + red[2] + red[3];
            if (co == 0) wsf[SCALE_IDX] = powf(16.0f / log1pf(256.0f), alpha[0]);
        }
        if (co == 0 && t >= 8 && t < 16) wsf[ZERO_IDX + (t - 8)] = 0.f;
    }
}

// ---------------- per-patch squared norm: one wave per output pixel ----------------
__global__ void k_psq(const U16* __restrict__ xt, float* __restrict__ wsf) {
    int t = threadIdx.x, lane = t & 63, wv = t >> 6;
    int gm = blockIdx.x * 4 + wv;                  // < 25088 exactly
    int ow = gm % 28, tt = gm / 28;
    int oh = tt % 28, n = tt / 28;
    const U16* xb = xt + (size_t)n * 56 * 56 * 128;
    float s = 0.f;
#pragma unroll
    for (int kh = 0; kh < 3; ++kh) {
        int ih = oh * 2 - 1 + kh;
        if ((unsigned)ih >= 56) continue;
#pragma unroll
        for (int kw = 0; kw < 3; ++kw) {
            int iw = ow * 2 - 1 + kw;
            if ((unsigned)iw >= 56) continue;
            unsigned int v = *(const unsigned int*)&xb[(size_t)((ih * 56 + iw) << 7) + lane * 2];
            float f0 = b2f((U16)(v & 0xffff)), f1 = b2f((U16)(v >> 16));
            s += f0 * f0 + f1 * f1;
        }
    }
#pragma unroll
    for (int off = 32; off >= 1; off >>= 1) s += __shfl_xor(s, off);
    if (lane == 0) wsf[PSQ_IDX + gm] = s;
}

// ---------------- MFMA implicit-GEMM, BM=64 BN=128 BK=64, double-buffered gl_lds ----------------
// MODE 0: yat dot conv (3x3 s2 p1 over xt) -> ybuf bf16; fused 1x1 s2 shortcut -> out (f32 NCHW)
// MODE 2: 3x3 s1 p1 over ybuf, out += v
template<int KTOT, int MODE>
__launch_bounds__(256)
__global__ void k_gemm(const U16* __restrict__ Asrc, const U16* __restrict__ Bp,
                       const U16* __restrict__ B2p,
                       const float* __restrict__ wsf, U16* __restrict__ ybuf,
                       float* __restrict__ out) {
    __shared__ U16 Abuf[2][64 * 64];               // 2 x 8 KB
    __shared__ U16 Btb[2][128 * 64];               // 2 x 16 KB
    __shared__ float psq_s[64];
    __shared__ float wsq_s[128];

    constexpr int NK = KTOT / 64;

    int t = threadIdx.x, lane = t & 63, wv = t >> 6;
    int wr = wv >> 1, wc = wv & 1;                 // wave tile: rows wr*32, cols wc*64
    int bid = blockIdx.x;
    int m0 = (bid >> 1) * 64;
    int co_base = (bid & 1) * 128;

    if (MODE == 0) {
        if (t < 64)                 psq_s[t] = wsf[PSQ_IDX + m0 + t];
        else if (t < 192)           wsq_s[t - 64] = wsf[WSQ_IDX + co_base + (t - 64)];
    }

    const U16* zptr = (const U16*)&wsf[ZERO_IDX];

    // A-staging: thread t stages rows r0 and r0+32 (16B each), LDS dest linear in t
    int r0 = t >> 3, phys = t & 7;
    int aplog = phys ^ (r0 & 7);                   // (r0+32)&7 == r0&7 -> same swizzle
    int am0 = m0 + r0, am1 = am0 + 32;
    int an0, aoh0, aow0, an1, aoh1, aow1;
    { int tt = am0 / 28; aow0 = am0 - tt * 28; an0 = tt / 28; aoh0 = tt - an0 * 28; }
    { int tt = am1 / 28; aow1 = am1 - tt * 28; an1 = tt / 28; aoh1 = tt - an1 * 28; }

    // B-staging: thread t stages cols bcol, +32, +64, +96
    int bcol = t >> 3;
    int bplog = phys ^ (bcol & 7);                 // (bcol+32)&7 == bcol&7
    const U16* bbase = Bp + (size_t)(co_base + bcol) * KTOT + bplog * 8;

    f32x4 acc[2][4] = {};
    f32x4 acc2[2][4] = {};                         // identity (MODE0)

    auto stage = [&](int ks, int sel) {
        int k0 = ks * 64;
        if (MODE == 0) {
            int khkw = k0 >> 7, ci0 = k0 & 127;
            int kh = khkw / 3, kw = khkw - 3 * kh;
            int ih0 = aoh0 * 2 - 1 + kh, iw0 = aow0 * 2 - 1 + kw;
            int ih1 = aoh1 * 2 - 1 + kh, iw1 = aow1 * 2 - 1 + kw;
            bool v0 = ((unsigned)ih0 < 56) & ((unsigned)iw0 < 56);
            bool v1 = ((unsigned)ih1 < 56) & ((unsigned)iw1 < 56);
            const U16* s0 = v0 ? Asrc + ((size_t)((an0 * 56 + ih0) * 56 + iw0) << 7) + ci0 + aplog * 8 : zptr;
            const U16* s1 = v1 ? Asrc + ((size_t)((an1 * 56 + ih1) * 56 + iw1) << 7) + ci0 + aplog * 8 : zptr;
            gl_lds16(s0, &Abuf[sel][(size_t)t * 8]);
            gl_lds16(s1, &Abuf[sel][(size_t)(256 + t) * 8]);
        } else {
            int khkw = k0 >> 8, cy0 = k0 & 255;
            int kh = khkw / 3, kw = khkw - 3 * kh;
            int ih0 = aoh0 - 1 + kh, iw0 = aow0 - 1 + kw;
            int ih1 = aoh1 - 1 + kh, iw1 = aow1 - 1 + kw;
            bool v0 = ((unsigned)ih0 < 28) & ((unsigned)iw0 < 28);
            bool v1 = ((unsigned)ih1 < 28) & ((unsigned)iw1 < 28);
            const U16* s0 = v0 ? Asrc + ((size_t)((an0 * 28 + ih0) * 28 + iw0) << 8) + cy0 + aplog * 8 : zptr;
            const U16* s1 = v1 ? Asrc + ((size_t)((an1 * 28 + ih1) * 28 + iw1) << 8) + cy0 + aplog * 8 : zptr;
            gl_lds16(s0, &Abuf[sel][(size_t)t * 8]);
            gl_lds16(s1, &Abuf[sel][(size_t)(256 + t) * 8]);
        }
#pragma unroll
        for (int r = 0; r < 4; ++r)
            gl_lds16(bbase + (size_t)r * 32 * KTOT + k0, &Btb[sel][(size_t)(r * 256 + t) * 8]);
    };

    stage(0, 0);
    __syncthreads();

    for (int ks = 0; ks < NK; ++ks) {
        int sel = ks & 1;
        if (ks + 1 < NK) stage(ks + 1, sel ^ 1);   // prefetch next tile (async)
        // ---- MFMA on buf[sel] ----
#pragma unroll
        for (int kk = 0; kk < 2; ++kk) {
            bf16x8 af[2], bfr[4];
#pragma unroll
            for (int i = 0; i < 2; ++i) {
                int row = wr * 32 + i * 16 + (lane & 15);
                int pp = (kk * 4 + (lane >> 4)) ^ (row & 7);
                af[i] = *(const bf16x8*)&Abuf[sel][(row * 8 + pp) * 8];
            }
#pragma unroll
            for (int j = 0; j < 4; ++j) {
                int col = wc * 64 + j * 16 + (lane & 15);
                int pp = (kk * 4 + (lane >> 4)) ^ (col & 7);
                bfr[j] = *(const bf16x8*)&Btb[sel][(col * 8 + pp) * 8];
            }
#pragma unroll
            for (int i = 0; i < 2; ++i)
#pragma unroll
                for (int j = 0; j < 4; ++j)
                    acc[i][j] = __builtin_amdgcn_mfma_f32_16x16x32_bf16(af[i], bfr[j], acc[i][j], 0, 0, 0);
            if (MODE == 0) {
                if (ks == 8 || ks == 9) {          // center tap: fused 1x1 shortcut, B2 via registers
#pragma unroll
                    for (int j = 0; j < 4; ++j) {
                        int col = wc * 64 + j * 16 + (lane & 15);
                        int q = kk * 4 + (lane >> 4);
                        bf16x8 b2v = *(const bf16x8*)&B2p[(size_t)(co_base + col) * 128 + (ks - 8) * 64 + q * 8];
#pragma unroll
                        for (int i = 0; i < 2; ++i)
                            acc2[i][j] = __builtin_amdgcn_mfma_f32_16x16x32_bf16(af[i], b2v, acc2[i][j], 0, 0, 0);
                    }
                }
            }
        }
        __syncthreads();   // drains own prefetch (vmcnt 0) + protects buf reuse
    }

    // ---- epilogue ----
    float scale = (MODE == 0) ? wsf[SCALE_IDX] : 0.f;
#pragma unroll
    for (int i = 0; i < 2; ++i)
#pragma unroll
        for (int j = 0; j < 4; ++j)
#pragma unroll
            for (int r = 0; r < 4; ++r) {
                int row = wr * 32 + i * 16 + ((lane >> 4) << 2) + r;
                int coll = wc * 64 + j * 16 + (lane & 15);
                float v = acc[i][j][r];
                int m = m0 + row;
                int ow = m % 28, tt2 = m / 28;
                int oh = tt2 % 28, n = tt2 / 28;
                int co = co_base + coll;
                size_t oidx = ((size_t)(n * 256 + co) * 28 + oh) * 28 + ow;
                if (MODE == 0) {
                    float dist = psq_s[row] + wsq_s[coll] - 2.0f * v + EPS_;
                    float y = v * v / dist * scale;
                    ybuf[(size_t)m * 256 + co] = f2bf(y);
                    out[oidx] = acc2[i][j][r];
                } else {
                    out[oidx] += v;
                }
            }
}

extern "C" void kernel_launch(void* const* d_in, const int* in_sizes, int n_in,
                              void* d_out, int out_size, void* d_ws, size_t ws_size,
                              hipStream_t stream) {
    const float* x       = (const float*)d_in[0];
    const float* w_yat   = (const float*)d_in[1];
    const float* alpha   = (const float*)d_in[2];
    const float* w_lin   = (const float*)d_in[3];
    const float* w_short = (const float*)d_in[4];
    float* out = (float*)d_out;
    float* wsf = (float*)d_ws;

    U16* xt = (U16*)((char*)d_ws + U16_BYTE_OFF);
    U16* yb = xt + (size_t)N_ * H_ * W_ * CIN;        // 12,845,056
    U16* B1 = yb + (size_t)M_ * COUT;                 // +6,422,528
    U16* B2 = B1 + 1152 * COUT;                       // +294,912
    U16* B3 = B2 + CIN * COUT;                        // +32,768   (B3: 589,824)

    k_prep<<<10112, 256, 0, stream>>>(x, w_yat, w_lin, w_short, alpha, xt, B1, B3, B2, wsf);
    k_psq <<<6272,  256, 0, stream>>>(xt, wsf);

    k_gemm<1152, 0><<<784, 256, 0, stream>>>(xt, B1, B2, wsf, yb, out);
    k_gemm<2304, 2><<<784, 256, 0, stream>>>(yb, B3, nullptr, wsf, nullptr, out);
}

// Round 5
// 171.300 us; speedup vs baseline: 1.1433x; 1.1433x over previous
//
#include <hip/hip_runtime.h>
#include <math.h>

#define N_    32
#define CIN   128
#define H_    56
#define W_    56
#define COUT  256
#define OH    28
#define OW    28
#define M_    (N_ * OH * OW)      // 25088
#define EPS_  0.007f

typedef unsigned short U16;
typedef float f32x4  __attribute__((ext_vector_type(4)));
typedef short bf16x8 __attribute__((ext_vector_type(8)));

// ws float-region layout
#define SCALE_IDX 0
#define ZERO_IDX  8             // wsf[8..15]: 32B zero page for OOB global_load_lds
#define WSQ_IDX   16            // 256 floats
#define PSQ_IDX   512           // 25088 floats
#define U16_BYTE_OFF 102400     // = 25600 floats, 256B aligned

__device__ __forceinline__ U16 f2bf(float f) {
    unsigned int u = __builtin_bit_cast(unsigned int, f);
    u = (u + 0x7fffu + ((u >> 16) & 1u)) >> 16;   // RNE
    return (U16)u;
}
__device__ __forceinline__ float b2f(U16 h) {
    unsigned int u = ((unsigned int)h) << 16;
    return __builtin_bit_cast(float, u);
}

__device__ __forceinline__ void gl_lds16(const U16* g, U16* l) {
    __builtin_amdgcn_global_load_lds((const __attribute__((address_space(1))) void*)g,
                                     (__attribute__((address_space(3))) void*)l, 16, 0, 0);
}

// ---------------- fused prep: x transpose + weight reorder + wsq/scale/zero ----------------
__global__ void k_prep(const float* __restrict__ x,
                       const float* __restrict__ w_yat,
                       const float* __restrict__ w_lin,
                       const float* __restrict__ w_short,
                       const float* __restrict__ alpha,
                       U16* __restrict__ xt, U16* __restrict__ B1,
                       U16* __restrict__ B3, U16* __restrict__ B2,
                       float* __restrict__ wsf) {
    int b = blockIdx.x, t = threadIdx.x;
    if (b < 6272) {
        int idx = b * 256 + t;                     // 1,605,632 exactly
        int ci8 = idx & 15;
        int px  = idx >> 4;                        // n*3136 + hw
        int n   = px / 3136;
        int hw  = px - n * 3136;
        const float* src = x + ((size_t)n * 128 + ci8 * 8) * 3136 + hw;
        unsigned int o[4];
#pragma unroll
        for (int j = 0; j < 4; ++j) {
            float a = src[(size_t)(2 * j)     * 3136];
            float c = src[(size_t)(2 * j + 1) * 3136];
            o[j] = (unsigned)f2bf(a) | ((unsigned)f2bf(c) << 16);
        }
        *(uint4*)&xt[(size_t)px * 128 + ci8 * 8] = *(const uint4*)o;
    } else if (b < 9856) {
        int idx = (b - 6272) * 256 + t;            // 917,504 exactly
        if (idx < 294912) {
            int co = idx / 1152, k = idx % 1152;
            int khkw = k >> 7, ci = k & 127;
            B1[idx] = f2bf(w_yat[(co * 128 + ci) * 9 + khkw]);
        } else if (idx < 294912 + 589824) {
            int i2 = idx - 294912;
            int co = i2 / 2304, k = i2 % 2304;
            int khkw = k >> 8, cy = k & 255;
            B3[i2] = f2bf(w_lin[(co * 256 + cy) * 9 + khkw]);
        } else {
            int i3 = idx - (294912 + 589824);      // < 32768
            B2[i3] = f2bf(w_short[i3]);
        }
    } else {
        int co = b - 9856, lane = t & 63, wv = t >> 6;
        const float* wc = w_yat + (size_t)co * 1152;
        float s = 0.f;
        for (int i = t; i < 1152; i += 256) { float v = wc[i]; s += v * v; }
#pragma unroll
        for (int off = 32; off >= 1; off >>= 1) s += __shfl_xor(s, off);
        __shared__ float red[4];
        if (lane == 0) red[wv] = s;
        __syncthreads();
        if (t == 0) {
            wsf[WSQ_IDX + co] = red[0] + red[1] + red[2] + red[3];
            if (co == 0) wsf[SCALE_IDX] = powf(16.0f / log1pf(256.0f), alpha[0]);
        }
        if (co == 0 && t >= 8 && t < 16) wsf[ZERO_IDX + (t - 8)] = 0.f;
    }
}

// ---------------- per-patch squared norm: one wave per output pixel ----------------
__global__ void k_psq(const U16* __restrict__ xt, float* __restrict__ wsf) {
    int t = threadIdx.x, lane = t & 63, wv = t >> 6;
    int gm = blockIdx.x * 4 + wv;                  // < 25088 exactly
    int ow = gm % 28, tt = gm / 28;
    int oh = tt % 28, n = tt / 28;
    const U16* xb = xt + (size_t)n * 56 * 56 * 128;
    float s = 0.f;
#pragma unroll
    for (int kh = 0; kh < 3; ++kh) {
        int ih = oh * 2 - 1 + kh;
        if ((unsigned)ih >= 56) continue;
#pragma unroll
        for (int kw = 0; kw < 3; ++kw) {
            int iw = ow * 2 - 1 + kw;
            if ((unsigned)iw >= 56) continue;
            unsigned int v = *(const unsigned int*)&xb[(size_t)((ih * 56 + iw) << 7) + lane * 2];
            float f0 = b2f((U16)(v & 0xffff)), f1 = b2f((U16)(v >> 16));
            s += f0 * f0 + f1 * f1;
        }
    }
#pragma unroll
    for (int off = 32; off >= 1; off >>= 1) s += __shfl_xor(s, off);
    if (lane == 0) wsf[PSQ_IDX + gm] = s;
}

// ---------------- MFMA implicit-GEMM, BM=128 BN=128 BK=64 ----------------
// Static double-buffer (4 distinct LDS arrays -> provable non-alias -> no vmcnt
// serialization before ds_read). 4 waves, each owns a 64x64 quadrant (4x4 frags).
// MODE 0: yat dot conv (3x3 s2 p1 over xt) -> ybuf bf16; fused 1x1 s2 shortcut -> out
// MODE 2: 3x3 s1 p1 over ybuf, out += v
template<int KTOT, int MODE>
__launch_bounds__(256)
__global__ void k_gemm(const U16* __restrict__ Asrc, const U16* __restrict__ Bp,
                       const U16* __restrict__ B2p,
                       const float* __restrict__ wsf, U16* __restrict__ ybuf,
                       float* __restrict__ out) {
    __shared__ U16 A0[128 * 64];                   // 16 KB each
    __shared__ U16 A1[128 * 64];
    __shared__ U16 Bb0[128 * 64];
    __shared__ U16 Bb1[128 * 64];
    __shared__ float psq_s[128];
    __shared__ float wsq_s[128];

    constexpr int NK = KTOT / 64;                  // 18 or 36 (even)

    int t = threadIdx.x, lane = t & 63, wv = t >> 6;
    int wr = wv >> 1, wc = wv & 1;                 // wave quadrant: rows wr*64, cols wc*64
    int bid = blockIdx.x;
    int m0 = (bid >> 1) * 128;
    int co_base = (bid & 1) * 128;

    if (MODE == 0) {
        if (t < 128)  psq_s[t] = wsf[PSQ_IDX + m0 + t];
        else          wsq_s[t - 128] = wsf[WSQ_IDX + co_base + (t - 128)];
    }

    const U16* zptr = (const U16*)&wsf[ZERO_IDX];

    // A-staging: thread t stages rows r0+32*rr (rr=0..3), 16B each; LDS dest linear
    int r0 = t >> 3, phys = t & 7;
    int aplog = phys ^ (r0 & 7);                   // (r0+32*rr)&7 == r0&7
    int an[4], aoh[4], aow[4];
#pragma unroll
    for (int rr = 0; rr < 4; ++rr) {
        int am = m0 + r0 + 32 * rr;
        int tt = am / 28; aow[rr] = am - tt * 28; an[rr] = tt / 28; aoh[rr] = tt - an[rr] * 28;
    }

    // B-staging: thread t stages cols bcol+32*r (r=0..3)
    int bcol = t >> 3;
    int bplog = phys ^ (bcol & 7);
    const U16* bbase = Bp + (size_t)(co_base + bcol) * KTOT + bplog * 8;

    f32x4 acc[4][4] = {};
    f32x4 acc2[4][4] = {};                         // identity (MODE0 only; DCE'd in MODE2)

    auto stage = [&](int ks, U16* Ab, U16* Bb) {
        int k0 = ks * 64;
        if (MODE == 0) {
            int khkw = k0 >> 7, ci0 = k0 & 127;
            int kh = khkw / 3, kw = khkw - 3 * kh;
#pragma unroll
            for (int rr = 0; rr < 4; ++rr) {
                int ih = aoh[rr] * 2 - 1 + kh, iw = aow[rr] * 2 - 1 + kw;
                bool v = ((unsigned)ih < 56) & ((unsigned)iw < 56);
                const U16* s = v ? Asrc + ((size_t)((an[rr] * 56 + ih) * 56 + iw) << 7) + ci0 + aplog * 8 : zptr;
                gl_lds16(s, &Ab[(size_t)(rr * 256 + t) * 8]);
            }
        } else {
            int khkw = k0 >> 8, cy0 = k0 & 255;
            int kh = khkw / 3, kw = khkw - 3 * kh;
#pragma unroll
            for (int rr = 0; rr < 4; ++rr) {
                int ih = aoh[rr] - 1 + kh, iw = aow[rr] - 1 + kw;
                bool v = ((unsigned)ih < 28) & ((unsigned)iw < 28);
                const U16* s = v ? Asrc + ((size_t)((an[rr] * 28 + ih) * 28 + iw) << 8) + cy0 + aplog * 8 : zptr;
                gl_lds16(s, &Ab[(size_t)(rr * 256 + t) * 8]);
            }
        }
#pragma unroll
        for (int r = 0; r < 4; ++r)
            gl_lds16(bbase + (size_t)r * 32 * KTOT + k0, &Bb[(size_t)(r * 256 + t) * 8]);
    };

    auto compute = [&](int ks, const U16* Ab, const U16* Bb) {
#pragma unroll
        for (int kk = 0; kk < 2; ++kk) {
            bf16x8 af[4], bfr[4];
#pragma unroll
            for (int i = 0; i < 4; ++i) {
                int row = wr * 64 + i * 16 + (lane & 15);
                int pp = (kk * 4 + (lane >> 4)) ^ (row & 7);
                af[i] = *(const bf16x8*)&Ab[(row * 8 + pp) * 8];
            }
#pragma unroll
            for (int j = 0; j < 4; ++j) {
                int col = wc * 64 + j * 16 + (lane & 15);
                int pp = (kk * 4 + (lane >> 4)) ^ (col & 7);
                bfr[j] = *(const bf16x8*)&Bb[(col * 8 + pp) * 8];
            }
#pragma unroll
            for (int i = 0; i < 4; ++i)
#pragma unroll
                for (int j = 0; j < 4; ++j)
                    acc[i][j] = __builtin_amdgcn_mfma_f32_16x16x32_bf16(af[i], bfr[j], acc[i][j], 0, 0, 0);
            if (MODE == 0 && (ks == 8 || ks == 9)) {   // center tap: fused 1x1 shortcut
#pragma unroll
                for (int j = 0; j < 4; ++j) {
                    int col = wc * 64 + j * 16 + (lane & 15);
                    int q = kk * 4 + (lane >> 4);
                    bf16x8 b2v = *(const bf16x8*)&B2p[(size_t)(co_base + col) * 128 + (ks - 8) * 64 + q * 8];
#pragma unroll
                    for (int i = 0; i < 4; ++i)
                        acc2[i][j] = __builtin_amdgcn_mfma_f32_16x16x32_bf16(af[i], b2v, acc2[i][j], 0, 0, 0);
                }
            }
        }
    };

    stage(0, A0, Bb0);
    __syncthreads();

    for (int ks = 0; ks < NK; ks += 2) {
        stage(ks + 1, A1, Bb1);                    // prefetch odd tile (async, lands under compute)
        compute(ks, A0, Bb0);
        __syncthreads();
        if (ks + 2 < NK) stage(ks + 2, A0, Bb0);   // prefetch next even tile
        compute(ks + 1, A1, Bb1);
        __syncthreads();
    }

    // ---- epilogue ----
    float scale = (MODE == 0) ? wsf[SCALE_IDX] : 0.f;
#pragma unroll
    for (int i = 0; i < 4; ++i)
#pragma unroll
        for (int j = 0; j < 4; ++j)
#pragma unroll
            for (int r = 0; r < 4; ++r) {
                int row = wr * 64 + i * 16 + ((lane >> 4) << 2) + r;
                int coll = wc * 64 + j * 16 + (lane & 15);
                float v = acc[i][j][r];
                int m = m0 + row;
                int ow = m % 28, tt2 = m / 28;
                int oh = tt2 % 28, n = tt2 / 28;
                int co = co_base + coll;
                size_t oidx = ((size_t)(n * 256 + co) * 28 + oh) * 28 + ow;
                if (MODE == 0) {
                    float dist = psq_s[row] + wsq_s[coll] - 2.0f * v + EPS_;
                    float y = v * v / dist * scale;
                    ybuf[(size_t)m * 256 + co] = f2bf(y);
                    out[oidx] = acc2[i][j][r];
                } else {
                    out[oidx] += v;
                }
            }
}

extern "C" void kernel_launch(void* const* d_in, const int* in_sizes, int n_in,
                              void* d_out, int out_size, void* d_ws, size_t ws_size,
                              hipStream_t stream) {
    const float* x       = (const float*)d_in[0];
    const float* w_yat   = (const float*)d_in[1];
    const float* alpha   = (const float*)d_in[2];
    const float* w_lin   = (const float*)d_in[3];
    const float* w_short = (const float*)d_in[4];
    float* out = (float*)d_out;
    float* wsf = (float*)d_ws;

    U16* xt = (U16*)((char*)d_ws + U16_BYTE_OFF);
    U16* yb = xt + (size_t)N_ * H_ * W_ * CIN;        // 12,845,056
    U16* B1 = yb + (size_t)M_ * COUT;                 // +6,422,528
    U16* B2 = B1 + 1152 * COUT;                       // +294,912
    U16* B3 = B2 + CIN * COUT;                        // +32,768   (B3: 589,824)

    k_prep<<<10112, 256, 0, stream>>>(x, w_yat, w_lin, w_short, alpha, xt, B1, B3, B2, wsf);
    k_psq <<<6272,  256, 0, stream>>>(xt, wsf);

    k_gemm<1152, 0><<<392, 256, 0, stream>>>(xt, B1, B2, wsf, yb, out);
    k_gemm<2304, 2><<<392, 256, 0, stream>>>(yb, B3, nullptr, wsf, nullptr, out);
}